// Round 4
// baseline (336.229 us; speedup 1.0000x reference)
//
#include <hip/hip_runtime.h>

typedef __attribute__((ext_vector_type(8))) __bf16 bf16x8;
typedef __attribute__((ext_vector_type(4))) float f32x4;
typedef __attribute__((ext_vector_type(4))) short short4v;

#define MFMA16(a,b,c)  __builtin_amdgcn_mfma_f32_16x16x32_bf16((a),(b),(c),0,0,0)
#define MFMA16K(a,b,c) __builtin_amdgcn_mfma_f32_16x16x16bf16_1k((a),(b),(c),0,0,0)

__device__ __forceinline__ short f2bf(float f){
  union { float f; unsigned u; } x; x.f = f;
  return (short)((x.u + 0x7fffu + ((x.u >> 16) & 1u)) >> 16);
}
__device__ __forceinline__ unsigned bits(float f){
  union { float f; unsigned u; } x; x.f = f; return x.u;
}

__device__ __forceinline__ void gld16(void* lds, const void* g){
  __builtin_amdgcn_global_load_lds(
      (const __attribute__((address_space(1))) unsigned*)g,
      (__attribute__((address_space(3))) unsigned*)lds, 16, 0, 0);
}

// ---------------- elementwise converts / transposes ----------------

__global__ __launch_bounds__(256) void k_cvt8(const float* __restrict__ x,
                                              short* __restrict__ xb){
  long i = (long)blockIdx.x * 256 + threadIdx.x;       // groups of 8
  const float4* xv = (const float4*)x;
  float4 a = xv[2*i], c = xv[2*i+1];
  short s[8] = {f2bf(a.x),f2bf(a.y),f2bf(a.z),f2bf(a.w),
                f2bf(c.x),f2bf(c.y),f2bf(c.z),f2bf(c.w)};
  *(uint4*)&xb[8*i] = *(uint4*)s;
}

// W fp32 [2048][N] row-major -> Wt bf16 [N][2048]
__global__ void k_wt(const float* __restrict__ W, short* __restrict__ Wt, int N){
  __shared__ float tile[32][33];
  int tx = threadIdx.x, ty = threadIdx.y;
  int k0 = blockIdx.y*32, n0 = blockIdx.x*32;
  for (int j=0;j<32;j+=8)
    tile[ty+j][tx] = W[(size_t)(k0+ty+j)*N + n0 + tx];
  __syncthreads();
  for (int j=0;j<32;j+=8)
    Wt[(size_t)(n0+ty+j)*2048 + k0 + tx] = f2bf(tile[tx][ty+j]);
}

__global__ void k_bias(const float* __restrict__ bq, const float* __restrict__ bk,
                       const float* __restrict__ bv, float* __restrict__ outb){
  int i = blockIdx.x*256 + threadIdx.x;   // 0..3071
  float v = (i < 2048) ? bq[i] : (i < 2560 ? bk[i-2048] : bv[i-2560]);
  outb[i] = v;
}

// v-part of qkv (bf16, rows 4096, cols 2560..3071 of ld 3072) -> Vt[b][kvh][d][t]
__global__ void k_vt(const short* __restrict__ qkv, short* __restrict__ Vt){
  __shared__ short tile[32][33];
  int tx = threadIdx.x, ty = threadIdx.y;
  int t0 = blockIdx.x*32, c0 = blockIdx.y*32;
  for (int j=0;j<32;j+=8)
    tile[ty+j][tx] = qkv[(size_t)(t0+ty+j)*3072 + 2560 + c0 + tx];
  __syncthreads();
  int b = t0 >> 11, t_in_b = t0 & 2047;
  for (int j=0;j<32;j+=8){
    int col = c0 + ty + j;               // 0..511
    int kvh = col >> 7, d = col & 127;
    Vt[((size_t)((b*4 + kvh)*128 + d))*2048 + t_in_b + tx] = tile[tx][ty+j];
  }
}

// ---------------- m97-style GEMM: C = A * Bt^T + bias ----------------
// XCD-chunked bijective block swizzle (T1): nwg%8==0 for both call sites
// (768, 512). Pure permutation of (m0,n0) assignment — numerics unchanged.
template<int OUT_BF16>
__global__ __launch_bounds__(256) void gemm_bt(const short* __restrict__ A,
    const short* __restrict__ Bt, const float* __restrict__ bias,
    void* __restrict__ Cv, int M, int N, int K){
  __shared__ short As[128*32];
  __shared__ short Bs[128*32];
  const int tid = threadIdx.x;
  const int w = tid >> 6, lane = tid & 63, l15 = lane & 15, quad = lane >> 4;
  const int wr = w >> 1, wc = w & 1;
  const int nbx = gridDim.x;
  const int lin = blockIdx.y * nbx + blockIdx.x;
  const int cpx = (nbx * gridDim.y) >> 3;
  const int swz = (lin & 7) * cpx + (lin >> 3);
  const int m0 = (swz / nbx) * 128, n0 = (swz % nbx) * 128;
  const int lrow = lane >> 2, lcol = (lane & 3)*8;
  const short* Ag = A  + (size_t)(m0 + w*32 + lrow)*K + lcol;
  const short* Bg = Bt + (size_t)(n0 + w*32 + lrow)*K + lcol;
  short* AsW0 = &As[(w*32)*32];
  short* AsW1 = &As[(w*32+16)*32];
  short* BsW0 = &Bs[(w*32)*32];
  short* BsW1 = &Bs[(w*32+16)*32];
  const size_t r16K = (size_t)16*K;
  f32x4 acc[4][4] = {};
  for (int kt = 0; kt < K; kt += 32){
    gld16(AsW0, Ag + kt);
    gld16(AsW1, Ag + kt + r16K);
    gld16(BsW0, Bg + kt);
    gld16(BsW1, Bg + kt + r16K);
    __syncthreads();
    bf16x8 af[4], bfr[4];
#pragma unroll
    for (int i=0;i<4;i++){
      af[i]  = *(const bf16x8*)&As[(wr*64 + i*16 + l15)*32 + quad*8];
      bfr[i] = *(const bf16x8*)&Bs[(wc*64 + i*16 + l15)*32 + quad*8];
    }
#pragma unroll
    for (int mi=0;mi<4;mi++)
#pragma unroll
      for (int nj=0;nj<4;nj++)
        acc[mi][nj] = MFMA16(af[mi], bfr[nj], acc[mi][nj]);
    __syncthreads();
  }
  float bv[4];
#pragma unroll
  for (int nj=0;nj<4;nj++) bv[nj] = bias[n0 + wc*64 + nj*16 + l15];
#pragma unroll
  for (int mi=0;mi<4;mi++){
    int row = m0 + wr*64 + mi*16 + quad*4;
#pragma unroll
    for (int nj=0;nj<4;nj++){
      int col = n0 + wc*64 + nj*16 + l15;
#pragma unroll
      for (int r=0;r<4;r++){
        float v = acc[mi][nj][r] + bv[nj];
        if (OUT_BF16) ((short*)Cv)[(size_t)(row+r)*N + col] = f2bf(v);
        else          ((float*)Cv)[(size_t)(row+r)*N + col] = v;
      }
    }
  }
}

// ---------------- balanced, async-pipelined causal GQA attention ----------
// (byte-identical to the round-1 PASSING kernel, plus inert s_setprio hints
// around the two MFMA clusters — T5.)
// 256 threads (4 waves x 16 q rows). Block = pair of q-tiles (qi, 31-qi) at
// BQ=64 -> uniform 68 s-tile iters/block. Double-buffered LDS, K/V staged
// with global_load_lds into XOR-swizzled unpadded tiles, ONE barrier/iter.
// S^T = K*Q^T (16x16x32), P in registers, O^T += V^T*P^T (16x16x16).
__global__ __launch_bounds__(256) void k_attn(const short* __restrict__ qkv,
                                              const short* __restrict__ Vt,
                                              short* __restrict__ attn){
  constexpr float COEF = 0.12752365f;     // (1/sqrt(128)) * log2(e)
  __shared__ short SM[16384];             // 2 buffers x (K 4096 + V 4096 shorts)
  const int tid = threadIdx.x, w = tid >> 6, lane = tid & 63;
  const int l15 = lane & 15, quad = lane >> 4;
  const int p = blockIdx.x, h = blockIdx.y, b = blockIdx.z, kvh = h >> 2;

  // staging source pointers (per-lane); each wave stages 1/4 of each tile
  const short* kb[2];
  const short* vb[2];
#pragma unroll
  for (int j=0;j<2;j++){
    int rK = w*8 + j*4 + (lane >> 4);            // s-row 0..31
    int cK = (lane & 15) ^ (rK & 15);            // 8-short chunk of d
    kb[j] = qkv + (size_t)(b*2048 + rK)*3072 + 2048 + kvh*128 + cK*8;
    int dV = w*32 + j*16 + (lane >> 2);          // d-row 0..127
    int cV = (lane & 3) ^ (dV & 3) ^ ((dV >> 2) & 3);  // 8-short chunk of s
    vb[j] = Vt + ((size_t)((b*4 + kvh)*128 + dV))*2048 + cV*8;
  }
  short* K0 = &SM[w*1024];                // wave's slot base, buf 0
  short* V0 = &SM[4096 + w*1024];

  int buf = 0;
  // prologue: stage tile 0 of strip 0 into buf 0
#pragma unroll
  for (int j=0;j<2;j++){
    gld16(K0 + j*512, kb[j]);
    gld16(V0 + j*512, vb[j]);
  }

  for (int sp = 0; sp < 2; sp++){
    const int qi = sp ? (31 - p) : p;
    const int qw = qi*64 + w*16;          // this wave's 16 q rows
    // Q fragments from global (B-operand layout: lane q=l15, k contiguous)
    bf16x8 qf[4];
    {
      const short* qbase = qkv + ((size_t)(b*2048 + qw + l15))*3072 + h*128 + quad*8;
#pragma unroll
      for (int d4=0;d4<4;d4++)
        qf[d4] = *(const bf16x8*)(qbase + d4*32);
    }
    f32x4 accO[8] = {};
    float lsum = 0.f;
    const int nst = 2*qi + 2;

    for (int st = 0; st < nst; st++){
      __syncthreads();                       // tile(st) in LDS[buf] complete
      const int cur = buf;
      const int nb = buf ^ 1;
      // async-stage next tile (or next strip's tile 0) into other buffer
      {
        int nxt = -1;
        if (st + 1 < nst) nxt = (st + 1) * 32;
        else if (sp == 0) nxt = 0;
        if (nxt >= 0){
          short* Kd = &SM[nb*8192 + w*1024];
          short* Vd = &SM[nb*8192 + 4096 + w*1024];
          const size_t ko = (size_t)nxt * 3072;
#pragma unroll
          for (int j=0;j<2;j++){
            gld16(Kd + j*512, kb[j] + ko);
            gld16(Vd + j*512, vb[j] + nxt);
          }
        }
      }
      const int s0 = st * 32;
      if (s0 <= qw + 15){                    // wave-uniform skip
        const short* Kb = &SM[cur*8192];
        const short* Vb = &SM[cur*8192 + 4096];
        bf16x8 kf[2][4];
#pragma unroll
        for (int ss=0;ss<2;ss++)
#pragma unroll
          for (int d4=0;d4<4;d4++){
            int slot = (ss*16 + l15)*16 + ((d4*4 + quad) ^ l15);
            kf[ss][d4] = *(const bf16x8*)&Kb[slot*8];
          }
        f32x4 sa[2] = {};
        __builtin_amdgcn_s_setprio(1);
#pragma unroll
        for (int d4=0;d4<4;d4++){
          sa[0] = MFMA16(kf[0][d4], qf[d4], sa[0]);
          sa[1] = MFMA16(kf[1][d4], qf[d4], sa[1]);
        }
        __builtin_amdgcn_s_setprio(0);
        short4v pf[2];
        const bool mneed = (s0 + 31 > qw);
        const int qgl = qw + l15;
#pragma unroll
        for (int sub=0;sub<2;sub++){
          float pr[4];
#pragma unroll
          for (int r=0;r<4;r++){
            float e = __builtin_amdgcn_exp2f(sa[sub][r] * COEF);
            int sg = s0 + sub*16 + quad*4 + r;
            if (mneed && (sg > qgl)) e = 0.f;
            pr[r] = e;
          }
          lsum += (pr[0]+pr[1]) + (pr[2]+pr[3]);
          union { unsigned u[2]; short4v s; } pk;
          pk.u[0] = __builtin_amdgcn_perm(bits(pr[1]), bits(pr[0]), 0x07060302u);
          pk.u[1] = __builtin_amdgcn_perm(bits(pr[3]), bits(pr[2]), 0x07060302u);
          pf[sub] = pk.s;
        }
        // O^T += V^T * P^T
        __builtin_amdgcn_s_setprio(1);
#pragma unroll
        for (int sub=0;sub<2;sub++)
#pragma unroll
          for (int dt=0;dt<8;dt++){
            int slot = (dt*16 + l15)*4 +
                       ((sub*2 + (quad>>1)) ^ (l15 & 3) ^ ((l15 >> 2) & 3));
            short4v vf = *(const short4v*)&Vb[slot*8 + (quad&1)*4];
            accO[dt] = MFMA16K(vf, pf[sub], accO[dt]);
          }
        __builtin_amdgcn_s_setprio(0);
      }
      buf = nb;
    }
    // normalize + store this strip
    {
      float s = lsum;
      s += __shfl_xor(s, 16);
      s += __shfl_xor(s, 32);
      float inv = 1.0f / s;
      short* obase = attn + ((size_t)(b*2048 + qw + l15))*2048 + h*128 + quad*4;
#pragma unroll
      for (int dt=0;dt<8;dt++){
        float o0 = accO[dt][0]*inv, o1 = accO[dt][1]*inv;
        float o2 = accO[dt][2]*inv, o3 = accO[dt][3]*inv;
        union { unsigned u[2]; short4v s; } ok;
        ok.u[0] = __builtin_amdgcn_perm(bits(o1), bits(o0), 0x07060302u);
        ok.u[1] = __builtin_amdgcn_perm(bits(o3), bits(o2), 0x07060302u);
        *(short4v*)(obase + dt*16) = ok.s;
      }
    }
  }
}

// ---------------- launcher ----------------
extern "C" void kernel_launch(void* const* d_in, const int* in_sizes, int n_in,
                              void* d_out, int out_size, void* d_ws, size_t ws_size,
                              hipStream_t stream){
  const float* x  = (const float*)d_in[0];
  const float* Wq = (const float*)d_in[1];
  const float* bq = (const float*)d_in[2];
  const float* Wk = (const float*)d_in[3];
  const float* bk = (const float*)d_in[4];
  const float* Wv = (const float*)d_in[5];
  const float* bv = (const float*)d_in[6];
  const float* Wo = (const float*)d_in[7];
  const float* bo = (const float*)d_in[8];
  float* out = (float*)d_out;
  char* ws = (char*)d_ws;

  short* xb    = (short*)(ws + 0);                        // 16 MB
  short* WtQKV = (short*)(ws + (size_t)16*1024*1024);     // 12 MB [3072][2048]
  short* WoT   = (short*)(ws + (size_t)28*1024*1024);     //  8 MB [2048][2048]
  float* biasQ = (float*)(ws + (size_t)36*1024*1024);     // 12 KB
  short* qkv   = (short*)(ws + (size_t)37*1024*1024);     // 24 MB [4096][3072]
  short* Vt    = (short*)(ws + (size_t)61*1024*1024);     //  4 MB [B][KVH][128][2048]
  short* attn  = (short*)(ws + 0);                        // overlay xb (disjoint lifetime)

  k_cvt8<<<4096, 256, 0, stream>>>(x, xb);
  k_wt<<<dim3(64,64), dim3(32,8), 0, stream>>>(Wq, WtQKV, 2048);
  k_wt<<<dim3(16,64), dim3(32,8), 0, stream>>>(Wk, WtQKV + (size_t)2048*2048, 512);
  k_wt<<<dim3(16,64), dim3(32,8), 0, stream>>>(Wv, WtQKV + (size_t)2560*2048, 512);
  k_wt<<<dim3(64,64), dim3(32,8), 0, stream>>>(Wo, WoT, 2048);
  k_bias<<<12, 256, 0, stream>>>(bq, bk, bv, biasQ);
  gemm_bt<1><<<dim3(24,32), 256, 0, stream>>>(xb, WtQKV, biasQ, qkv, 4096, 3072, 2048);
  k_vt<<<dim3(128,16), dim3(32,8), 0, stream>>>(qkv, Vt);
  k_attn<<<dim3(16,16,2), 256, 0, stream>>>(qkv, Vt, attn);
  gemm_bt<0><<<dim3(16,32), 256, 0, stream>>>(attn, WoT, bo, out, 4096, 2048, 2048);
}

// Round 5
// 313.169 us; speedup vs baseline: 1.0736x; 1.0736x over previous
//
#include <hip/hip_runtime.h>

typedef __attribute__((ext_vector_type(8))) __bf16 bf16x8;
typedef __attribute__((ext_vector_type(4))) float f32x4;
typedef __attribute__((ext_vector_type(4))) short short4v;

#define MFMA16(a,b,c)  __builtin_amdgcn_mfma_f32_16x16x32_bf16((a),(b),(c),0,0,0)
#define MFMA16K(a,b,c) __builtin_amdgcn_mfma_f32_16x16x16bf16_1k((a),(b),(c),0,0,0)

__device__ __forceinline__ short f2bf(float f){
  union { float f; unsigned u; } x; x.f = f;
  return (short)((x.u + 0x7fffu + ((x.u >> 16) & 1u)) >> 16);
}
__device__ __forceinline__ unsigned bits(float f){
  union { float f; unsigned u; } x; x.f = f; return x.u;
}

__device__ __forceinline__ void gld16(void* lds, const void* g){
  __builtin_amdgcn_global_load_lds(
      (const __attribute__((address_space(1))) unsigned*)g,
      (__attribute__((address_space(3))) unsigned*)lds, 16, 0, 0);
}

template<int N>
__device__ __forceinline__ void s_wait_vmcnt(){
  if constexpr (N==8)      asm volatile("s_waitcnt vmcnt(8)" ::: "memory");
  else if constexpr (N==6) asm volatile("s_waitcnt vmcnt(6)" ::: "memory");
  else if constexpr (N==4) asm volatile("s_waitcnt vmcnt(4)" ::: "memory");
  else                     asm volatile("s_waitcnt vmcnt(0)" ::: "memory");
}

// ---------------- elementwise converts / transposes ----------------

__global__ __launch_bounds__(256) void k_cvt8(const float* __restrict__ x,
                                              short* __restrict__ xb){
  long i = (long)blockIdx.x * 256 + threadIdx.x;       // groups of 8
  const float4* xv = (const float4*)x;
  float4 a = xv[2*i], c = xv[2*i+1];
  short s[8] = {f2bf(a.x),f2bf(a.y),f2bf(a.z),f2bf(a.w),
                f2bf(c.x),f2bf(c.y),f2bf(c.z),f2bf(c.w)};
  *(uint4*)&xb[8*i] = *(uint4*)s;
}

// W fp32 [2048][N] row-major -> Wt bf16 [N][2048]
__global__ void k_wt(const float* __restrict__ W, short* __restrict__ Wt, int N){
  __shared__ float tile[32][33];
  int tx = threadIdx.x, ty = threadIdx.y;
  int k0 = blockIdx.y*32, n0 = blockIdx.x*32;
  for (int j=0;j<32;j+=8)
    tile[ty+j][tx] = W[(size_t)(k0+ty+j)*N + n0 + tx];
  __syncthreads();
  for (int j=0;j<32;j+=8)
    Wt[(size_t)(n0+ty+j)*2048 + k0 + tx] = f2bf(tile[tx][ty+j]);
}

__global__ void k_bias(const float* __restrict__ bq, const float* __restrict__ bk,
                       const float* __restrict__ bv, float* __restrict__ outb){
  int i = blockIdx.x*256 + threadIdx.x;   // 0..3071
  float v = (i < 2048) ? bq[i] : (i < 2560 ? bk[i-2048] : bv[i-2560]);
  outb[i] = v;
}

// v-part of qkv (bf16, rows 4096, cols 2560..3071 of ld 3072) -> Vt[b][kvh][d][t]
__global__ void k_vt(const short* __restrict__ qkv, short* __restrict__ Vt){
  __shared__ short tile[32][33];
  int tx = threadIdx.x, ty = threadIdx.y;
  int t0 = blockIdx.x*32, c0 = blockIdx.y*32;
  for (int j=0;j<32;j+=8)
    tile[ty+j][tx] = qkv[(size_t)(t0+ty+j)*3072 + 2560 + c0 + tx];
  __syncthreads();
  int b = t0 >> 11, t_in_b = t0 & 2047;
  for (int j=0;j<32;j+=8){
    int col = c0 + ty + j;               // 0..511
    int kvh = col >> 7, d = col & 127;
    Vt[((size_t)((b*4 + kvh)*128 + d))*2048 + t_in_b + tx] = tile[tx][ty+j];
  }
}

// ---------------- 256x256 / BK=64 phase-split GEMM: C = A * Bt^T + bias ----
// 512 threads = 8 waves (2M x 4N). Per wave: 128x64 output as acc[Ah][4][Bh][2].
// LDS 128 KiB: 2 dbuf x (A 256x64 + B 256x64) bf16, granule XOR-swizzle
// phys = g ^ (row&7) (inverse applied on global source, gld16 dest linear).
// Per K-tile: 4 phases {vmcnt-wait -> barrier -> stage 1 half -> ds_read
// subtile -> setprio(1) 16xMFMA setprio(0)}; counted vmcnt(8)/(6) at phases
// 1-2 (loads stay in flight across barriers); stages run 1 tile + 2 halves
// ahead. K accumulation order identical to the m97 kernel (tiles ascending,
// kk=0 then kk=32 per fragment) -> outputs bit-identical.
template<int OUT_BF16>
__global__ __launch_bounds__(512, 2) void gemm8(const short* __restrict__ A,
    const short* __restrict__ Bt, const float* __restrict__ bias,
    void* __restrict__ Cv, int M, int N, int K){
  __shared__ short SM[65536];                 // 128 KiB
  const int tid = threadIdx.x;
  const int w = tid >> 6, lane = tid & 63, l15 = lane & 15, quad = lane >> 4;
  const int wr = w >> 2, wc = w & 3;
  const int m0 = blockIdx.y * 256, n0 = blockIdx.x * 256;
  const int ln8 = lane >> 3;
  const int g8 = (((lane & 7) ^ (ln8 & 7)) << 3);          // src granule (shorts)
  const short* aB = A  + (size_t)(m0 + w*16 + ln8) * K + g8;
  const short* bB = Bt + (size_t)(n0 + w*16 + ln8) * K + g8;
  const int aRB = (wr*64 + l15)*64;
  const int bRB = (wc*32 + l15)*64;
  const int phys0 = (((quad    ) ^ (l15 & 7)) << 3);       // kk=0 granule
  const int phys1 = (((quad + 4) ^ (l15 & 7)) << 3);       // kk=32 granule
  f32x4 acc[2][4][2][2] = {};
  bf16x8 aF[4][2], bLo[2][2], bHi[2][2];
  const int nt = K >> 6;

#define STG_A(bufi, Ah, T)  do{ \
    short* d_ = &SM[(bufi)*32768 + ((Ah)*128 + w*16)*64]; \
    const short* s_ = aB + (size_t)((Ah)*128)*K + (size_t)(T)*64; \
    gld16(d_,      s_); \
    gld16(d_+512,  s_ + (size_t)8*K); }while(0)
#define STG_B(bufi, Bh, T)  do{ \
    short* d_ = &SM[(bufi)*32768 + 16384 + ((Bh)*128 + w*16)*64]; \
    const short* s_ = bB + (size_t)((Bh)*128)*K + (size_t)(T)*64; \
    gld16(d_,      s_); \
    gld16(d_+512,  s_ + (size_t)8*K); }while(0)
#define RD_A(bufi, Ah) do{ \
    const short* p_ = &SM[(bufi)*32768 + ((Ah)*128)*64 + aRB]; \
    _Pragma("unroll") for(int m_=0;m_<4;m_++){ \
      aF[m_][0] = *(const bf16x8*)&p_[m_*1024 + phys0]; \
      aF[m_][1] = *(const bf16x8*)&p_[m_*1024 + phys1]; } }while(0)
#define RD_B(bufi, Bh, dst) do{ \
    const short* p_ = &SM[(bufi)*32768 + 16384 + ((Bh)*128)*64 + bRB]; \
    _Pragma("unroll") for(int n_=0;n_<2;n_++){ \
      dst[n_][0] = *(const bf16x8*)&p_[n_*1024 + phys0]; \
      dst[n_][1] = *(const bf16x8*)&p_[n_*1024 + phys1]; } }while(0)
#define MM(Ah, Bh, bsrc) do{ __builtin_amdgcn_s_setprio(1); \
    _Pragma("unroll") for(int m_=0;m_<4;m_++) \
    _Pragma("unroll") for(int n_=0;n_<2;n_++){ \
      acc[Ah][m_][Bh][n_] = MFMA16(aF[m_][0], bsrc[n_][0], acc[Ah][m_][Bh][n_]); \
      acc[Ah][m_][Bh][n_] = MFMA16(aF[m_][1], bsrc[n_][1], acc[Ah][m_][Bh][n_]); } \
    __builtin_amdgcn_s_setprio(0); }while(0)
#define GROUP(T, STHI, STLO, W1, W2) do{ \
    const int c_ = (T)&1, nc_ = c_^1; \
    s_wait_vmcnt<W1>(); \
    __builtin_amdgcn_s_barrier(); \
    __builtin_amdgcn_sched_barrier(0); \
    if (STHI) STG_A(nc_, 1, (T)+1); \
    RD_A(c_, 0); RD_B(c_, 0, bLo); \
    MM(0, 0, bLo); \
    s_wait_vmcnt<W2>(); \
    __builtin_amdgcn_s_barrier(); \
    __builtin_amdgcn_sched_barrier(0); \
    if (STHI) STG_B(nc_, 1, (T)+1); \
    RD_B(c_, 1, bHi); \
    MM(0, 1, bHi); \
    __builtin_amdgcn_s_barrier(); \
    __builtin_amdgcn_sched_barrier(0); \
    if (STLO) STG_A(c_, 0, (T)+2); \
    RD_A(c_, 1); \
    MM(1, 0, bLo); \
    __builtin_amdgcn_s_barrier(); \
    __builtin_amdgcn_sched_barrier(0); \
    if (STLO) STG_B(c_, 0, (T)+2); \
    MM(1, 1, bHi); \
  }while(0)

  // prologue: lo(0), hi(0), lo(1)  (FIFO order matters for the counted waits)
  STG_A(0, 0, 0); STG_B(0, 0, 0);
  STG_A(0, 1, 0); STG_B(0, 1, 0);
  STG_A(1, 0, 1); STG_B(1, 0, 1);

  for (int T = 0; T < nt-2; ++T) GROUP(T, true, true, 8, 6);
  GROUP(nt-2, true,  false, 8, 6);
  GROUP(nt-1, false, false, 4, 0);

#undef GROUP
#undef MM
#undef RD_B
#undef RD_A
#undef STG_B
#undef STG_A

  // epilogue (same arithmetic as m97 kernel: acc + bias, then f2bf/float)
  float bv[2][2];
#pragma unroll
  for (int Bh=0;Bh<2;Bh++)
#pragma unroll
    for (int n=0;n<2;n++)
      bv[Bh][n] = bias[n0 + Bh*128 + wc*32 + n*16 + l15];
#pragma unroll
  for (int Ah=0;Ah<2;Ah++)
#pragma unroll
  for (int m=0;m<4;m++){
    int row = m0 + Ah*128 + wr*64 + m*16 + quad*4;
#pragma unroll
    for (int Bh=0;Bh<2;Bh++)
#pragma unroll
    for (int n=0;n<2;n++){
      int col = n0 + Bh*128 + wc*32 + n*16 + l15;
#pragma unroll
      for (int r=0;r<4;r++){
        float v = acc[Ah][m][Bh][n][r] + bv[Bh][n];
        if (OUT_BF16) ((short*)Cv)[(size_t)(row+r)*N + col] = f2bf(v);
        else          ((float*)Cv)[(size_t)(row+r)*N + col] = v;
      }
    }
  }
}

// ---------------- balanced, async-pipelined causal GQA attention ----------
// (byte-identical to the round-4 PASSING kernel.)
__global__ __launch_bounds__(256) void k_attn(const short* __restrict__ qkv,
                                              const short* __restrict__ Vt,
                                              short* __restrict__ attn){
  constexpr float COEF = 0.12752365f;     // (1/sqrt(128)) * log2(e)
  __shared__ short SM[16384];             // 2 buffers x (K 4096 + V 4096 shorts)
  const int tid = threadIdx.x, w = tid >> 6, lane = tid & 63;
  const int l15 = lane & 15, quad = lane >> 4;
  const int p = blockIdx.x, h = blockIdx.y, b = blockIdx.z, kvh = h >> 2;

  // staging source pointers (per-lane); each wave stages 1/4 of each tile
  const short* kb[2];
  const short* vb[2];
#pragma unroll
  for (int j=0;j<2;j++){
    int rK = w*8 + j*4 + (lane >> 4);            // s-row 0..31
    int cK = (lane & 15) ^ (rK & 15);            // 8-short chunk of d
    kb[j] = qkv + (size_t)(b*2048 + rK)*3072 + 2048 + kvh*128 + cK*8;
    int dV = w*32 + j*16 + (lane >> 2);          // d-row 0..127
    int cV = (lane & 3) ^ (dV & 3) ^ ((dV >> 2) & 3);  // 8-short chunk of s
    vb[j] = Vt + ((size_t)((b*4 + kvh)*128 + dV))*2048 + cV*8;
  }
  short* K0 = &SM[w*1024];                // wave's slot base, buf 0
  short* V0 = &SM[4096 + w*1024];

  int buf = 0;
  // prologue: stage tile 0 of strip 0 into buf 0
#pragma unroll
  for (int j=0;j<2;j++){
    gld16(K0 + j*512, kb[j]);
    gld16(V0 + j*512, vb[j]);
  }

  for (int sp = 0; sp < 2; sp++){
    const int qi = sp ? (31 - p) : p;
    const int qw = qi*64 + w*16;          // this wave's 16 q rows
    // Q fragments from global (B-operand layout: lane q=l15, k contiguous)
    bf16x8 qf[4];
    {
      const short* qbase = qkv + ((size_t)(b*2048 + qw + l15))*3072 + h*128 + quad*8;
#pragma unroll
      for (int d4=0;d4<4;d4++)
        qf[d4] = *(const bf16x8*)(qbase + d4*32);
    }
    f32x4 accO[8] = {};
    float lsum = 0.f;
    const int nst = 2*qi + 2;

    for (int st = 0; st < nst; st++){
      __syncthreads();                       // tile(st) in LDS[buf] complete
      const int cur = buf;
      const int nb = buf ^ 1;
      // async-stage next tile (or next strip's tile 0) into other buffer
      {
        int nxt = -1;
        if (st + 1 < nst) nxt = (st + 1) * 32;
        else if (sp == 0) nxt = 0;
        if (nxt >= 0){
          short* Kd = &SM[nb*8192 + w*1024];
          short* Vd = &SM[nb*8192 + 4096 + w*1024];
          const size_t ko = (size_t)nxt * 3072;
#pragma unroll
          for (int j=0;j<2;j++){
            gld16(Kd + j*512, kb[j] + ko);
            gld16(Vd + j*512, vb[j] + nxt);
          }
        }
      }
      const int s0 = st * 32;
      if (s0 <= qw + 15){                    // wave-uniform skip
        const short* Kb = &SM[cur*8192];
        const short* Vb = &SM[cur*8192 + 4096];
        bf16x8 kf[2][4];
#pragma unroll
        for (int ss=0;ss<2;ss++)
#pragma unroll
          for (int d4=0;d4<4;d4++){
            int slot = (ss*16 + l15)*16 + ((d4*4 + quad) ^ l15);
            kf[ss][d4] = *(const bf16x8*)&Kb[slot*8];
          }
        f32x4 sa[2] = {};
        __builtin_amdgcn_s_setprio(1);
#pragma unroll
        for (int d4=0;d4<4;d4++){
          sa[0] = MFMA16(kf[0][d4], qf[d4], sa[0]);
          sa[1] = MFMA16(kf[1][d4], qf[d4], sa[1]);
        }
        __builtin_amdgcn_s_setprio(0);
        short4v pf[2];
        const bool mneed = (s0 + 31 > qw);
        const int qgl = qw + l15;
#pragma unroll
        for (int sub=0;sub<2;sub++){
          float pr[4];
#pragma unroll
          for (int r=0;r<4;r++){
            float e = __builtin_amdgcn_exp2f(sa[sub][r] * COEF);
            int sg = s0 + sub*16 + quad*4 + r;
            if (mneed && (sg > qgl)) e = 0.f;
            pr[r] = e;
          }
          lsum += (pr[0]+pr[1]) + (pr[2]+pr[3]);
          union { unsigned u[2]; short4v s; } pk;
          pk.u[0] = __builtin_amdgcn_perm(bits(pr[1]), bits(pr[0]), 0x07060302u);
          pk.u[1] = __builtin_amdgcn_perm(bits(pr[3]), bits(pr[2]), 0x07060302u);
          pf[sub] = pk.s;
        }
        // O^T += V^T * P^T
        __builtin_amdgcn_s_setprio(1);
#pragma unroll
        for (int sub=0;sub<2;sub++)
#pragma unroll
          for (int dt=0;dt<8;dt++){
            int slot = (dt*16 + l15)*4 +
                       ((sub*2 + (quad>>1)) ^ (l15 & 3) ^ ((l15 >> 2) & 3));
            short4v vf = *(const short4v*)&Vb[slot*8 + (quad&1)*4];
            accO[dt] = MFMA16K(vf, pf[sub], accO[dt]);
          }
        __builtin_amdgcn_s_setprio(0);
      }
      buf = nb;
    }
    // normalize + store this strip
    {
      float s = lsum;
      s += __shfl_xor(s, 16);
      s += __shfl_xor(s, 32);
      float inv = 1.0f / s;
      short* obase = attn + ((size_t)(b*2048 + qw + l15))*2048 + h*128 + quad*4;
#pragma unroll
      for (int dt=0;dt<8;dt++){
        float o0 = accO[dt][0]*inv, o1 = accO[dt][1]*inv;
        float o2 = accO[dt][2]*inv, o3 = accO[dt][3]*inv;
        union { unsigned u[2]; short4v s; } ok;
        ok.u[0] = __builtin_amdgcn_perm(bits(o1), bits(o0), 0x07060302u);
        ok.u[1] = __builtin_amdgcn_perm(bits(o3), bits(o2), 0x07060302u);
        *(short4v*)(obase + dt*16) = ok.s;
      }
    }
  }
}

// ---------------- launcher ----------------
extern "C" void kernel_launch(void* const* d_in, const int* in_sizes, int n_in,
                              void* d_out, int out_size, void* d_ws, size_t ws_size,
                              hipStream_t stream){
  const float* x  = (const float*)d_in[0];
  const float* Wq = (const float*)d_in[1];
  const float* bq = (const float*)d_in[2];
  const float* Wk = (const float*)d_in[3];
  const float* bk = (const float*)d_in[4];
  const float* Wv = (const float*)d_in[5];
  const float* bv = (const float*)d_in[6];
  const float* Wo = (const float*)d_in[7];
  const float* bo = (const float*)d_in[8];
  float* out = (float*)d_out;
  char* ws = (char*)d_ws;

  short* xb    = (short*)(ws + 0);                        // 16 MB
  short* WtQKV = (short*)(ws + (size_t)16*1024*1024);     // 12 MB [3072][2048]
  short* WoT   = (short*)(ws + (size_t)28*1024*1024);     //  8 MB [2048][2048]
  float* biasQ = (float*)(ws + (size_t)36*1024*1024);     // 12 KB
  short* qkv   = (short*)(ws + (size_t)37*1024*1024);     // 24 MB [4096][3072]
  short* Vt    = (short*)(ws + (size_t)61*1024*1024);     //  4 MB [B][KVH][128][2048]
  short* attn  = (short*)(ws + 0);                        // overlay xb (disjoint lifetime)

  k_cvt8<<<4096, 256, 0, stream>>>(x, xb);
  k_wt<<<dim3(64,64), dim3(32,8), 0, stream>>>(Wq, WtQKV, 2048);
  k_wt<<<dim3(16,64), dim3(32,8), 0, stream>>>(Wk, WtQKV + (size_t)2048*2048, 512);
  k_wt<<<dim3(16,64), dim3(32,8), 0, stream>>>(Wv, WtQKV + (size_t)2560*2048, 512);
  k_wt<<<dim3(64,64), dim3(32,8), 0, stream>>>(Wo, WoT, 2048);
  k_bias<<<12, 256, 0, stream>>>(bq, bk, bv, biasQ);
  gemm8<1><<<dim3(12,16), 512, 0, stream>>>(xb, WtQKV, biasQ, qkv, 4096, 3072, 2048);
  k_vt<<<dim3(128,16), dim3(32,8), 0, stream>>>(qkv, Vt);
  k_attn<<<dim3(16,16,2), 256, 0, stream>>>(qkv, Vt, attn);
  gemm8<0><<<dim3(8,16), 512, 0, stream>>>(attn, WoT, bo, out, 4096, 2048, 2048);
}

// Round 7
// 293.616 us; speedup vs baseline: 1.1451x; 1.0666x over previous
//
#include <hip/hip_runtime.h>

typedef __attribute__((ext_vector_type(8))) __bf16 bf16x8;
typedef __attribute__((ext_vector_type(4))) float f32x4;
typedef __attribute__((ext_vector_type(4))) short short4v;

#define MFMA16(a,b,c)  __builtin_amdgcn_mfma_f32_16x16x32_bf16((a),(b),(c),0,0,0)
#define MFMA16K(a,b,c) __builtin_amdgcn_mfma_f32_16x16x16bf16_1k((a),(b),(c),0,0,0)

__device__ __forceinline__ short f2bf(float f){
  union { float f; unsigned u; } x; x.f = f;
  return (short)((x.u + 0x7fffu + ((x.u >> 16) & 1u)) >> 16);
}
__device__ __forceinline__ unsigned bits(float f){
  union { float f; unsigned u; } x; x.f = f; return x.u;
}

__device__ __forceinline__ void gld16(void* lds, const void* g){
  __builtin_amdgcn_global_load_lds(
      (const __attribute__((address_space(1))) unsigned*)g,
      (__attribute__((address_space(3))) unsigned*)lds, 16, 0, 0);
}

template<int N>
__device__ __forceinline__ void s_wait_vmcnt(){
  if constexpr (N==8)      asm volatile("s_waitcnt vmcnt(8)" ::: "memory");
  else if constexpr (N==6) asm volatile("s_waitcnt vmcnt(6)" ::: "memory");
  else if constexpr (N==4) asm volatile("s_waitcnt vmcnt(4)" ::: "memory");
  else if constexpr (N==2) asm volatile("s_waitcnt vmcnt(2)" ::: "memory");
  else                     asm volatile("s_waitcnt vmcnt(0)" ::: "memory");
}

// ---------------- elementwise converts / transposes ----------------

__global__ __launch_bounds__(256) void k_cvt8(const float* __restrict__ x,
                                              short* __restrict__ xb){
  long i = (long)blockIdx.x * 256 + threadIdx.x;       // groups of 8
  const float4* xv = (const float4*)x;
  float4 a = xv[2*i], c = xv[2*i+1];
  short s[8] = {f2bf(a.x),f2bf(a.y),f2bf(a.z),f2bf(a.w),
                f2bf(c.x),f2bf(c.y),f2bf(c.z),f2bf(c.w)};
  *(uint4*)&xb[8*i] = *(uint4*)s;
}

// W fp32 [2048][N] row-major -> Wt bf16 [N][2048]
__global__ void k_wt(const float* __restrict__ W, short* __restrict__ Wt, int N){
  __shared__ float tile[32][33];
  int tx = threadIdx.x, ty = threadIdx.y;
  int k0 = blockIdx.y*32, n0 = blockIdx.x*32;
  for (int j=0;j<32;j+=8)
    tile[ty+j][tx] = W[(size_t)(k0+ty+j)*N + n0 + tx];
  __syncthreads();
  for (int j=0;j<32;j+=8)
    Wt[(size_t)(n0+ty+j)*2048 + k0 + tx] = f2bf(tile[tx][ty+j]);
}

__global__ void k_bias(const float* __restrict__ bq, const float* __restrict__ bk,
                       const float* __restrict__ bv, float* __restrict__ outb){
  int i = blockIdx.x*256 + threadIdx.x;   // 0..3071
  float v = (i < 2048) ? bq[i] : (i < 2560 ? bk[i-2048] : bv[i-2560]);
  outb[i] = v;
}

// v-part of qkv (bf16, rows 4096, cols 2560..3071 of ld 3072) -> Vt[b][kvh][d][t]
__global__ void k_vt(const short* __restrict__ qkv, short* __restrict__ Vt){
  __shared__ short tile[32][33];
  int tx = threadIdx.x, ty = threadIdx.y;
  int t0 = blockIdx.x*32, c0 = blockIdx.y*32;
  for (int j=0;j<32;j+=8)
    tile[ty+j][tx] = qkv[(size_t)(t0+ty+j)*3072 + 2560 + c0 + tx];
  __syncthreads();
  int b = t0 >> 11, t_in_b = t0 & 2047;
  for (int j=0;j<32;j+=8){
    int col = c0 + ty + j;               // 0..511
    int kvh = col >> 7, d = col & 127;
    Vt[((size_t)((b*4 + kvh)*128 + d))*2048 + t_in_b + tx] = tile[tx][ty+j];
  }
}

// -------- 128 x (BCH*128) / BK=64 phase-split GEMM: C = A * Bt^T + bias ----
// Rectangular variant of the round-5 gemm8, sized so grid = exactly 256
// blocks = 1 block/CU (QKV: 128x384, grid 8x32; O: 128x256, grid 8x32).
// 512 threads = 8 waves (2M x 4N). A = one 128-row chunk; B = BCH chunks of
// 128 rows. BCH phases per K-tile: {counted vmcnt -> barrier -> stage one
// chunk -> ds_read chunk -> setprio 16xMFMA}. Steady wait = 2*(BCH+1)
// (chunks in flight: T.B1..T.B_{BCH-1}, T+1.A, T+1.B0); stages run 1-2 tiles
// ahead; every LDS overwrite is issued >=1 barrier after the region's last
// read. Granule XOR-swizzle: source pre-swizzled (g ^ row&7), read applies
// the same XOR -> conflict-free ds_read_b128. Per-element K accumulation
// order identical to the m97/round-5 chain -> outputs bit-identical.
// N is the C row stride (output columns). Round-6 crash root-cause: the
// launcher passed N=4096 for the O-proj (stale M arg) -> OOB C writes.
template<int BCH, int OUT_BF16>
__global__ __launch_bounds__(512, 2) void gemmR(const short* __restrict__ A,
    const short* __restrict__ Bt, const float* __restrict__ bias,
    void* __restrict__ Cv, int N, int K){
  constexpr int ASZ  = 8192;                 // shorts in one 128x64 chunk
  constexpr int BUFS = ASZ*(1+BCH);
  __shared__ short SM[2*BUFS];
  const int tid = threadIdx.x;
  const int w = tid >> 6, lane = tid & 63, l15 = lane & 15, quad = lane >> 4;
  const int wr = w >> 2, wc = w & 3;
  const int m0 = blockIdx.y * 128, n0 = blockIdx.x * (BCH*128);
  const int ln8 = lane >> 3;
  const int g8 = (((lane & 7) ^ ln8) << 3);            // pre-swizzled src granule
  const short* aB = A  + (size_t)(m0 + w*16 + ln8) * K + g8;
  const short* bB = Bt + (size_t)(n0 + w*16 + ln8) * K + g8;
  const int aRB = (wr*64 + l15)*64;
  const int bRB = (wc*32 + l15)*64;
  const int phys0 = ((quad     ^ (l15 & 7)) << 3);     // kk=0..31 granule
  const int phys1 = (((quad+4) ^ (l15 & 7)) << 3);     // kk=32..63 granule
  f32x4 acc[BCH][4][2] = {};
  bf16x8 aF[4][2], bF[2][2];
  const int nt = K >> 6;

#define STG_A(bufi, T) do{ \
    short* d_ = &SM[(bufi)*BUFS + w*1024]; \
    const short* s_ = aB + (size_t)(T)*64; \
    gld16(d_, s_); gld16(d_+512, s_ + (size_t)8*K); }while(0)
#define STG_B(bufi, ch, T) do{ \
    short* d_ = &SM[(bufi)*BUFS + ASZ + (ch)*ASZ + w*1024]; \
    const short* s_ = bB + (size_t)((ch)*128)*K + (size_t)(T)*64; \
    gld16(d_, s_); gld16(d_+512, s_ + (size_t)8*K); }while(0)
#define RD_A(bufi) do{ const short* p_ = &SM[(bufi)*BUFS + aRB]; \
    _Pragma("unroll") for(int m_=0;m_<4;m_++){ \
      aF[m_][0] = *(const bf16x8*)&p_[m_*1024 + phys0]; \
      aF[m_][1] = *(const bf16x8*)&p_[m_*1024 + phys1]; } }while(0)
#define RD_B(bufi, ch) do{ const short* p_ = &SM[(bufi)*BUFS + ASZ + (ch)*ASZ + bRB]; \
    _Pragma("unroll") for(int n_=0;n_<2;n_++){ \
      bF[n_][0] = *(const bf16x8*)&p_[n_*1024 + phys0]; \
      bF[n_][1] = *(const bf16x8*)&p_[n_*1024 + phys1]; } }while(0)
#define MM(ch) do{ __builtin_amdgcn_s_setprio(1); \
    _Pragma("unroll") for(int m_=0;m_<4;m_++) \
    _Pragma("unroll") for(int n_=0;n_<2;n_++){ \
      acc[ch][m_][n_] = MFMA16(aF[m_][0], bF[n_][0], acc[ch][m_][n_]); \
      acc[ch][m_][n_] = MFMA16(aF[m_][1], bF[n_][1], acc[ch][m_][n_]); } \
    __builtin_amdgcn_s_setprio(0); }while(0)
#define PH(W) do{ s_wait_vmcnt<W>(); \
    __builtin_amdgcn_s_barrier(); \
    __builtin_amdgcn_sched_barrier(0); }while(0)
#define GROUP3(T, ST1, ST2, W0, W1, W2) do{ \
    const int c_=(T)&1, n_c=c_^1; \
    PH(W0); if (ST1) STG_B(n_c,1,(T)+1); RD_A(c_); RD_B(c_,0); MM(0); \
    PH(W1); if (ST1) STG_B(n_c,2,(T)+1); RD_B(c_,1); MM(1); \
    PH(W2); if (ST2){ STG_A(c_,(T)+2); STG_B(c_,0,(T)+2); } RD_B(c_,2); MM(2); \
  }while(0)
#define GROUP2(T, ST1, ST2, W0, W1) do{ \
    const int c_=(T)&1, n_c=c_^1; \
    PH(W0); if (ST1) STG_B(n_c,1,(T)+1); RD_A(c_); RD_B(c_,0); MM(0); \
    PH(W1); if (ST2){ STG_A(c_,(T)+2); STG_B(c_,0,(T)+2); } RD_B(c_,1); MM(1); \
  }while(0)

  if constexpr (BCH == 3){
    // prologue FIFO: T0.A,T0.B0,T0.B1,T0.B2,T1.A,T1.B0  (12 ops)
    STG_A(0,0); STG_B(0,0,0); STG_B(0,1,0); STG_B(0,2,0);
    STG_A(1,1); STG_B(1,0,1);
    for (int T = 0; T < nt-2; ++T) GROUP3(T, true, true, 8,8,8);
    GROUP3(nt-2, true,  false, 8,8,8);
    GROUP3(nt-1, false, false, 4,2,0);
  } else {
    // prologue FIFO: T0.A,T0.B0,T0.B1,T1.A,T1.B0  (10 ops)
    STG_A(0,0); STG_B(0,0,0); STG_B(0,1,0);
    STG_A(1,1); STG_B(1,0,1);
    for (int T = 0; T < nt-2; ++T) GROUP2(T, true, true, 6,6);
    GROUP2(nt-2, true,  false, 6,6);
    GROUP2(nt-1, false, false, 2,0);
  }

#undef GROUP2
#undef GROUP3
#undef PH
#undef MM
#undef RD_B
#undef RD_A
#undef STG_B
#undef STG_A

  // epilogue (same arithmetic as before: acc + bias, then f2bf/float)
  float bv[BCH][2];
#pragma unroll
  for (int ch=0; ch<BCH; ch++)
#pragma unroll
    for (int n=0; n<2; n++)
      bv[ch][n] = bias[n0 + ch*128 + wc*32 + n*16 + l15];
#pragma unroll
  for (int ch=0; ch<BCH; ch++)
#pragma unroll
  for (int m=0; m<4; m++){
    int row = m0 + wr*64 + m*16 + quad*4;
#pragma unroll
    for (int n=0; n<2; n++){
      int col = n0 + ch*128 + wc*32 + n*16 + l15;
#pragma unroll
      for (int r=0; r<4; r++){
        float v = acc[ch][m][n][r] + bv[ch][n];
        if (OUT_BF16) ((short*)Cv)[(size_t)(row+r)*N + col] = f2bf(v);
        else          ((float*)Cv)[(size_t)(row+r)*N + col] = v;
      }
    }
  }
}

// ---------------- balanced, async-pipelined causal GQA attention ----------
// (byte-identical to the round-4/5 PASSING kernel.)
__global__ __launch_bounds__(256) void k_attn(const short* __restrict__ qkv,
                                              const short* __restrict__ Vt,
                                              short* __restrict__ attn){
  constexpr float COEF = 0.12752365f;     // (1/sqrt(128)) * log2(e)
  __shared__ short SM[16384];             // 2 buffers x (K 4096 + V 4096 shorts)
  const int tid = threadIdx.x, w = tid >> 6, lane = tid & 63;
  const int l15 = lane & 15, quad = lane >> 4;
  const int p = blockIdx.x, h = blockIdx.y, b = blockIdx.z, kvh = h >> 2;

  // staging source pointers (per-lane); each wave stages 1/4 of each tile
  const short* kb[2];
  const short* vb[2];
#pragma unroll
  for (int j=0;j<2;j++){
    int rK = w*8 + j*4 + (lane >> 4);            // s-row 0..31
    int cK = (lane & 15) ^ (rK & 15);            // 8-short chunk of d
    kb[j] = qkv + (size_t)(b*2048 + rK)*3072 + 2048 + kvh*128 + cK*8;
    int dV = w*32 + j*16 + (lane >> 2);          // d-row 0..127
    int cV = (lane & 3) ^ (dV & 3) ^ ((dV >> 2) & 3);  // 8-short chunk of s
    vb[j] = Vt + ((size_t)((b*4 + kvh)*128 + dV))*2048 + cV*8;
  }
  short* K0 = &SM[w*1024];                // wave's slot base, buf 0
  short* V0 = &SM[4096 + w*1024];

  int buf = 0;
  // prologue: stage tile 0 of strip 0 into buf 0
#pragma unroll
  for (int j=0;j<2;j++){
    gld16(K0 + j*512, kb[j]);
    gld16(V0 + j*512, vb[j]);
  }

  for (int sp = 0; sp < 2; sp++){
    const int qi = sp ? (31 - p) : p;
    const int qw = qi*64 + w*16;          // this wave's 16 q rows
    // Q fragments from global (B-operand layout: lane q=l15, k contiguous)
    bf16x8 qf[4];
    {
      const short* qbase = qkv + ((size_t)(b*2048 + qw + l15))*3072 + h*128 + quad*8;
#pragma unroll
      for (int d4=0;d4<4;d4++)
        qf[d4] = *(const bf16x8*)(qbase + d4*32);
    }
    f32x4 accO[8] = {};
    float lsum = 0.f;
    const int nst = 2*qi + 2;

    for (int st = 0; st < nst; st++){
      __syncthreads();                       // tile(st) in LDS[buf] complete
      const int cur = buf;
      const int nb = buf ^ 1;
      // async-stage next tile (or next strip's tile 0) into other buffer
      {
        int nxt = -1;
        if (st + 1 < nst) nxt = (st + 1) * 32;
        else if (sp == 0) nxt = 0;
        if (nxt >= 0){
          short* Kd = &SM[nb*8192 + w*1024];
          short* Vd = &SM[nb*8192 + 4096 + w*1024];
          const size_t ko = (size_t)nxt * 3072;
#pragma unroll
          for (int j=0;j<2;j++){
            gld16(Kd + j*512, kb[j] + ko);
            gld16(Vd + j*512, vb[j] + nxt);
          }
        }
      }
      const int s0 = st * 32;
      if (s0 <= qw + 15){                    // wave-uniform skip
        const short* Kb = &SM[cur*8192];
        const short* Vb = &SM[cur*8192 + 4096];
        bf16x8 kf[2][4];
#pragma unroll
        for (int ss=0;ss<2;ss++)
#pragma unroll
          for (int d4=0;d4<4;d4++){
            int slot = (ss*16 + l15)*16 + ((d4*4 + quad) ^ l15);
            kf[ss][d4] = *(const bf16x8*)&Kb[slot*8];
          }
        f32x4 sa[2] = {};
        __builtin_amdgcn_s_setprio(1);
#pragma unroll
        for (int d4=0;d4<4;d4++){
          sa[0] = MFMA16(kf[0][d4], qf[d4], sa[0]);
          sa[1] = MFMA16(kf[1][d4], qf[d4], sa[1]);
        }
        __builtin_amdgcn_s_setprio(0);
        short4v pf[2];
        const bool mneed = (s0 + 31 > qw);
        const int qgl = qw + l15;
#pragma unroll
        for (int sub=0;sub<2;sub++){
          float pr[4];
#pragma unroll
          for (int r=0;r<4;r++){
            float e = __builtin_amdgcn_exp2f(sa[sub][r] * COEF);
            int sg = s0 + sub*16 + quad*4 + r;
            if (mneed && (sg > qgl)) e = 0.f;
            pr[r] = e;
          }
          lsum += (pr[0]+pr[1]) + (pr[2]+pr[3]);
          union { unsigned u[2]; short4v s; } pk;
          pk.u[0] = __builtin_amdgcn_perm(bits(pr[1]), bits(pr[0]), 0x07060302u);
          pk.u[1] = __builtin_amdgcn_perm(bits(pr[3]), bits(pr[2]), 0x07060302u);
          pf[sub] = pk.s;
        }
        // O^T += V^T * P^T
        __builtin_amdgcn_s_setprio(1);
#pragma unroll
        for (int sub=0;sub<2;sub++)
#pragma unroll
          for (int dt=0;dt<8;dt++){
            int slot = (dt*16 + l15)*4 +
                       ((sub*2 + (quad>>1)) ^ (l15 & 3) ^ ((l15 >> 2) & 3));
            short4v vf = *(const short4v*)&Vb[slot*8 + (quad&1)*4];
            accO[dt] = MFMA16K(vf, pf[sub], accO[dt]);
          }
        __builtin_amdgcn_s_setprio(0);
      }
      buf = nb;
    }
    // normalize + store this strip
    {
      float s = lsum;
      s += __shfl_xor(s, 16);
      s += __shfl_xor(s, 32);
      float inv = 1.0f / s;
      short* obase = attn + ((size_t)(b*2048 + qw + l15))*2048 + h*128 + quad*4;
#pragma unroll
      for (int dt=0;dt<8;dt++){
        float o0 = accO[dt][0]*inv, o1 = accO[dt][1]*inv;
        float o2 = accO[dt][2]*inv, o3 = accO[dt][3]*inv;
        union { unsigned u[2]; short4v s; } ok;
        ok.u[0] = __builtin_amdgcn_perm(bits(o1), bits(o0), 0x07060302u);
        ok.u[1] = __builtin_amdgcn_perm(bits(o3), bits(o2), 0x07060302u);
        *(short4v*)(obase + dt*16) = ok.s;
      }
    }
  }
}

// ---------------- launcher ----------------
extern "C" void kernel_launch(void* const* d_in, const int* in_sizes, int n_in,
                              void* d_out, int out_size, void* d_ws, size_t ws_size,
                              hipStream_t stream){
  const float* x  = (const float*)d_in[0];
  const float* Wq = (const float*)d_in[1];
  const float* bq = (const float*)d_in[2];
  const float* Wk = (const float*)d_in[3];
  const float* bk = (const float*)d_in[4];
  const float* Wv = (const float*)d_in[5];
  const float* bv = (const float*)d_in[6];
  const float* Wo = (const float*)d_in[7];
  const float* bo = (const float*)d_in[8];
  float* out = (float*)d_out;
  char* ws = (char*)d_ws;

  short* xb    = (short*)(ws + 0);                        // 16 MB
  short* WtQKV = (short*)(ws + (size_t)16*1024*1024);     // 12 MB [3072][2048]
  short* WoT   = (short*)(ws + (size_t)28*1024*1024);     //  8 MB [2048][2048]
  float* biasQ = (float*)(ws + (size_t)36*1024*1024);     // 12 KB
  short* qkv   = (short*)(ws + (size_t)37*1024*1024);     // 24 MB [4096][3072]
  short* Vt    = (short*)(ws + (size_t)61*1024*1024);     //  4 MB [B][KVH][128][2048]
  short* attn  = (short*)(ws + 0);                        // overlay xb (disjoint lifetime)

  k_cvt8<<<4096, 256, 0, stream>>>(x, xb);
  k_wt<<<dim3(64,64), dim3(32,8), 0, stream>>>(Wq, WtQKV, 2048);
  k_wt<<<dim3(16,64), dim3(32,8), 0, stream>>>(Wk, WtQKV + (size_t)2048*2048, 512);
  k_wt<<<dim3(16,64), dim3(32,8), 0, stream>>>(Wv, WtQKV + (size_t)2560*2048, 512);
  k_wt<<<dim3(64,64), dim3(32,8), 0, stream>>>(Wo, WoT, 2048);
  k_bias<<<12, 256, 0, stream>>>(bq, bk, bv, biasQ);
  gemmR<3,1><<<dim3(8,32), 512, 0, stream>>>(xb, WtQKV, biasQ, qkv, 3072, 2048);
  k_vt<<<dim3(128,16), dim3(32,8), 0, stream>>>(qkv, Vt);
  k_attn<<<dim3(16,16,2), 256, 0, stream>>>(qkv, Vt, attn);
  gemmR<2,0><<<dim3(8,32), 512, 0, stream>>>(attn, WoT, bo, out, 2048, 2048);
}